// Round 12
// baseline (144.956 us; speedup 1.0000x reference)
//
#include <hip/hip_runtime.h>
#include <hip/hip_fp16.h>

static constexpr int Hh = 384;
static constexpr int Ww = 1280;
static constexpr int HW = Hh * Ww;            // 491520
static constexpr int NPIX = 2 * HW;
static constexpr int TILE_I = 48;             // output tile rows
static constexpr int TILE_J = 40;             // output tile cols
static constexpr int S_STEPS = 12;            // steps per launch; 24 = 2 x 12
static constexpr int RI = TILE_I + 2 * S_STEPS;   // 72
static constexpr int RJ = TILE_J + 2 * S_STEPS;   // 64
static constexpr int RR = RI * RJ;            // 4608
static constexpr int II = RI - 2;             // 70 interior rows
static constexpr int IJ = RJ - 2;             // 62 interior cols
static constexpr int NPAIR_ROW = IJ / 2;      // 31 pairs/row (exact)
static constexpr int NPAIR = II * NPAIR_ROW;  // 2170 pairs
static constexpr int BLOCK = 512;
static constexpr int PPQ = RR / BLOCK;        // 9 region px / thread (exact)
static constexpr int PPR = (NPAIR + BLOCK - 1) / BLOCK;   // 5 pairs / thread
static constexpr int TI_T = Hh / TILE_I;      // 8
static constexpr int TJ_T = Ww / TILE_J;      // 32
static constexpr int GRID = 2 * TI_T * TJ_T;  // 512 = exactly 2 blocks/CU
static constexpr int NXCD = 8;
static constexpr int CHUNK = GRID / NXCD;     // 64 (512 % 8 == 0 -> bijective)
static constexpr float EPSF = 1e-9f;

// k order matches reference PADS: (di,dj) =
// k:   0       1       2       3       4       5       6       7
//    (+1,+1) (+1,0) (+1,-1) (0,+1) (0,-1) (-1,+1) (-1,0) (-1,-1)
static constexpr int DI[8] = { 1, 1, 1, 0, 0, -1, -1, -1 };
static constexpr int DJ[8] = { 1, 0, -1, 1, -1, 1, 0, -1 };

static __device__ __forceinline__ int iclamp(int v, int lo, int hi) {
    return min(max(v, lo), hi);
}

// Round-12: 2 launches x 12 fused steps (halo 12), tile 48x40, fp16 pair
// weights with v_fma_mix inner loop.
//
// Why (from the r8/r11 fit): per-launch time ~= (setup+stage ~10-12us) +
// 1.4us/M px-steps. Total barrier phases = 24 for ANY split; setup is paid
// per launch. 3x8 -> 2x12 cuts setup px 57% (10.3M -> 4.4M) and staged px
// 57%, while px-steps rise only 24% (32.0M -> 39.6M). One fewer launch,
// one fewer full drain.
//
// Config: BLOCK=512 + __launch_bounds__(512,2) = the only incantation that
// yields a 128-VGPR budget (knob ledger r3-r6). Grid 512 = exactly 2
// blocks/CU (LDS 36.9 KB x 2 = 73.7 KB <= 160). PPR=5 forces weights back
// to fp16-packed (r8-proven, absmax 1.0 << 3.48 threshold): persistent =
// wp 40 + Cc 10 + pr 5 = 55 regs -> no spill risk; fp32 would be 95 +
// temps (marginal). Inner loop: 6 aligned ds_read_b64 + 16 v_fma_mix +
// ds_write2.
//
//  - Pairs start at odd region col -> all +-RJ+-1 tap bases even -> 8B
//    aligned (RJ=64 even preserves parity across rows).
//  - Shrinking active set, pair-granular (r8/r11-verified): compute pair
//    if max(ring0,ring1) >= s; partner px below cutoff computes bounded
//    stale values never read by in-cutoff px later. Final step does exact
//    per-px center checks (maxring >= 12 -> ri in [12,60) = 48 tile rows;
//    cols gated per px to [12, 52) = 40 tile cols).
//  - Out-of-image region px hold clamped duplicates; never reach the
//    center (image-boundary px have weight 0 toward OOB neighbors, from
//    the reference's zero-padded guidance).
//  - blur/din NOT __restrict__ (r11 fix); launch 1 uses FIRST=true to
//    stage d0 from blur directly.
template <bool FIRST>
__global__ __launch_bounds__(BLOCK, 2)
void mega(
    const float* __restrict__ g,
    const float* blur,
    const float* __restrict__ sparse,
    const float* din,
    float* __restrict__ dout)
{
    __shared__ float sd[2][RR];

    const int tid = threadIdx.x;
    // XCD-aware bijective swizzle (512 = 8*64): neighbor tiles share halo
    // reads within one XCD's private L2.
    int bx = ((int)blockIdx.x % NXCD) * CHUNK + (int)blockIdx.x / NXCD;
    const int tj = bx % TJ_T; bx /= TJ_T;
    const int ti = bx % TI_T;
    const int b  = bx / TI_T;
    const int oi = ti * TILE_I - S_STEPS;  // region origin (image coords)
    const int oj = tj * TILE_J - S_STEPS;

    const float* blurb = blur + (size_t)b * HW;
    const float* dinb  = (FIRST ? blur : din) + (size_t)b * HW;
    const float* gb    = g + (size_t)b * 8 * HW;

    // --- stage d0 over the whole region (image-clamped; 9x512 exact) ---
#pragma unroll
    for (int q = 0; q < PPQ; q++) {
        int p = tid + q * BLOCK;
        int ri = p / RJ, rj = p - ri * RJ;
        int gi = iclamp(oi + ri, 0, Hh - 1);
        int gj = iclamp(oj + rj, 0, Ww - 1);
        sd[0][p] = dinb[gi * Ww + gj];
    }

    // --- fp16 weights + fp32 C per PAIR; registers for all 12 steps.
    // wp[q][k] = half2( w_k[px0], w_k[px1] ); Cc[q] = (C0, C1);
    // pr[q] = region offset of px0 (low 16) | max(ring0,ring1) << 16 ---
    __half2 wp[PPR][8];
    float2  Cc[PPR];
    int     pr[PPR];
#pragma unroll
    for (int q = 0; q < PPR; q++) {
        int pi = tid + q * BLOCK;
        if (pi < NPAIR) {
            int r0 = pi / NPAIR_ROW;
            int c0 = pi - r0 * NPAIR_ROW;
            int ri = 1 + r0;
            int rj = 1 + 2 * c0;           // odd -> aligned b64 tap bases
            int p  = ri * RJ + rj;
            int rngr = min(ri, RI - 1 - ri);
            int rng0 = min(rngr, min(rj,     RJ - 1 - rj));
            int rng1 = min(rngr, min(rj + 1, RJ - 2 - rj));
            pr[q] = p | (max(rng0, rng1) << 16);
            float Cv[2], wv[2][8];
#pragma unroll
            for (int x = 0; x < 2; x++) {
                int gi = iclamp(oi + ri, 0, Hh - 1);
                int gj = iclamp(oj + rj + x, 0, Ww - 1);
                float v[8];
                float a = EPSF;
#pragma unroll
                for (int k = 0; k < 8; k++) {
                    int ii = gi + DI[k], jj = gj + DJ[k];
                    float gv = 0.0f;
                    if (ii >= 0 && ii < Hh && jj >= 0 && jj < Ww)
                        gv = gb[k * HW + ii * Ww + jj];
                    v[k] = gv;
                    a += fabsf(gv);
                }
                float inv = 1.0f / a, gs = 0.0f;
#pragma unroll
                for (int k = 0; k < 8; k++) { v[k] *= inv; gs += v[k]; }
                int idx = gi * Ww + gj;
                float rawv = blurb[idx];
                bool m = sparse[b * HW + idx] > 0.0f; // sparse>=0; sign==1 iff >0
                Cv[x] = m ? rawv : (1.0f - gs) * rawv;
#pragma unroll
                for (int k = 0; k < 8; k++) wv[x][k] = m ? 0.0f : v[k];
            }
            Cc[q] = make_float2(Cv[0], Cv[1]);
#pragma unroll
            for (int k = 0; k < 8; k++)
                wp[q][k] = __halves2half2(__float2half(wv[0][k]),
                                          __float2half(wv[1][k]));
        } else {
            pr[q] = 0;                      // ring 0 -> never active
            Cc[q] = make_float2(0.0f, 0.0f);
#pragma unroll
            for (int k = 0; k < 8; k++)
                wp[q][k] = __halves2half2(__float2half(0.0f), __float2half(0.0f));
        }
    }
    __syncthreads();

    // --- steps 1..11 in LDS; step s touches only pairs with maxring >= s ---
    int cur = 0;
#pragma unroll 1
    for (int s = 1; s < S_STEPS; ++s) {
        const float* s0 = sd[cur];
        float* s1 = sd[cur ^ 1];
#pragma unroll
        for (int q = 0; q < PPR; q++) {
            if ((pr[q] >> 16) >= s) {
                int p = pr[q] & 0xffff;
                // 12 distinct taps as 6 aligned b64 loads
                float2 uA = *(const float2*)(s0 + p - RJ - 1);   // (i-1: j-1, j)
                float2 uB = *(const float2*)(s0 + p - RJ + 1);   // (i-1: j+1, j+2)
                float2 mA = *(const float2*)(s0 + p - 1);        // (i  : j-1, j)
                float2 mB = *(const float2*)(s0 + p + 1);        // (i  : j+1, j+2)
                float2 dA = *(const float2*)(s0 + p + RJ - 1);   // (i+1: j-1, j)
                float2 dB = *(const float2*)(s0 + p + RJ + 1);   // (i+1: j+1, j+2)
                float ax = Cc[q].x, ay = Cc[q].y;
                ax = fmaf(__low2float (wp[q][0]), dB.x, ax);
                ay = fmaf(__high2float(wp[q][0]), dB.y, ay);
                ax = fmaf(__low2float (wp[q][1]), dA.y, ax);
                ay = fmaf(__high2float(wp[q][1]), dB.x, ay);
                ax = fmaf(__low2float (wp[q][2]), dA.x, ax);
                ay = fmaf(__high2float(wp[q][2]), dA.y, ay);
                ax = fmaf(__low2float (wp[q][3]), mB.x, ax);
                ay = fmaf(__high2float(wp[q][3]), mB.y, ay);
                ax = fmaf(__low2float (wp[q][4]), mA.x, ax);
                ay = fmaf(__high2float(wp[q][4]), mA.y, ay);
                ax = fmaf(__low2float (wp[q][5]), uB.x, ax);
                ay = fmaf(__high2float(wp[q][5]), uB.y, ay);
                ax = fmaf(__low2float (wp[q][6]), uA.y, ax);
                ay = fmaf(__high2float(wp[q][6]), uB.x, ay);
                ax = fmaf(__low2float (wp[q][7]), uA.x, ax);
                ay = fmaf(__high2float(wp[q][7]), uA.y, ay);
                s1[p]     = ax;
                s1[p + 1] = ay;
            }
        }
        __syncthreads();
        cur ^= 1;
    }

    // --- step 12: per-px center checks, write straight to global ---
    const float* s0 = sd[cur];
#pragma unroll
    for (int q = 0; q < PPR; q++) {
        if ((pr[q] >> 16) >= S_STEPS) {
            int p = pr[q] & 0xffff;
            float2 uA = *(const float2*)(s0 + p - RJ - 1);
            float2 uB = *(const float2*)(s0 + p - RJ + 1);
            float2 mA = *(const float2*)(s0 + p - 1);
            float2 mB = *(const float2*)(s0 + p + 1);
            float2 dA = *(const float2*)(s0 + p + RJ - 1);
            float2 dB = *(const float2*)(s0 + p + RJ + 1);
            float ax = Cc[q].x, ay = Cc[q].y;
            ax = fmaf(__low2float (wp[q][0]), dB.x, ax);
            ay = fmaf(__high2float(wp[q][0]), dB.y, ay);
            ax = fmaf(__low2float (wp[q][1]), dA.y, ax);
            ay = fmaf(__high2float(wp[q][1]), dB.x, ay);
            ax = fmaf(__low2float (wp[q][2]), dA.x, ax);
            ay = fmaf(__high2float(wp[q][2]), dA.y, ay);
            ax = fmaf(__low2float (wp[q][3]), mB.x, ax);
            ay = fmaf(__high2float(wp[q][3]), mB.y, ay);
            ax = fmaf(__low2float (wp[q][4]), mA.x, ax);
            ay = fmaf(__high2float(wp[q][4]), mA.y, ay);
            ax = fmaf(__low2float (wp[q][5]), uB.x, ax);
            ay = fmaf(__high2float(wp[q][5]), uB.y, ay);
            ax = fmaf(__low2float (wp[q][6]), uA.y, ax);
            ay = fmaf(__high2float(wp[q][6]), uB.x, ay);
            ax = fmaf(__low2float (wp[q][7]), uA.x, ax);
            ay = fmaf(__high2float(wp[q][7]), uA.y, ay);
            int ri = p / RJ, rj = p - ri * RJ;
            // maxring >= 12 guarantees ri in [12, RI-12); cols per px.
            int gbase = b * HW + (oi + ri) * Ww + (oj + rj);
            if (rj >= S_STEPS && rj < RJ - S_STEPS)
                dout[gbase]     = ax;
            if (rj + 1 >= S_STEPS && rj + 1 < RJ - S_STEPS)
                dout[gbase + 1] = ay;
        }
    }
}

extern "C" void kernel_launch(void* const* d_in, const int* in_sizes, int n_in,
                              void* d_out, int out_size, void* d_ws, size_t ws_size,
                              hipStream_t stream) {
    const float* guidance = (const float*)d_in[0];
    const float* blur     = (const float*)d_in[1];
    const float* sparse   = (const float*)d_in[2];
    float* out = (float*)d_out;

    char* ws = (char*)d_ws;
    float* bufA = (float*)ws;

    // 24 steps = 2 launches x 12 fused steps
    mega<true ><<<GRID, BLOCK, 0, stream>>>(guidance, blur, sparse, nullptr, bufA);
    mega<false><<<GRID, BLOCK, 0, stream>>>(guidance, blur, sparse, bufA, out);
}